// Round 13
// baseline (285.365 us; speedup 1.0000x reference)
//
#include <hip/hip_runtime.h>
#include <hip/hip_bf16.h>

#define B_SZ    2
#define L_SEQ   2048
#define D_MODEL 384
#define D_INNER 768
#define D_STATE 16
#define DT_RANK 24
#define ML      (B_SZ * L_SEQ)   // 4096 rows
#define NCHUNK  64
#define CHLEN   (L_SEQ / NCHUNK) // 32

typedef __hip_bfloat16 bf16;
typedef __attribute__((ext_vector_type(8))) short bf16x8;
typedef __attribute__((ext_vector_type(4))) float f32x4;
typedef __attribute__((ext_vector_type(8))) float f32x8;

// ---------------------------------------------------------------------------
// in_proj GEMM, 128x128 tile. A fp32 [M][K], W fp32 [K][N].
// 256 thr / 4 waves (2x2); wave = 64x64 via 4x4 16x16x32 MFMA accs.
// Epilogue split transposed: outb0[n][m]=xp_raw (n<768), outb1[n-768][m]=silu(z).
// M=4096, N=1536, K=384 (all multiples of tile dims; no guards needed).
// Halves the redundant A/W L2 traffic vs the 64x64 tile (295 -> 147 MB).
// ---------------------------------------------------------------------------
__global__ __launch_bounds__(256)
void gemm_inproj_128(const float* __restrict__ Af, const float* __restrict__ W,
                     bf16* __restrict__ outb0, bf16* __restrict__ outb1,
                     int M, int N, int K)
{
    __shared__ __attribute__((aligned(16))) short As[128][72];
    __shared__ __attribute__((aligned(16))) short Bs[128][72];
    const int tid  = threadIdx.x;
    const int lane = tid & 63;
    const int wave = tid >> 6;
    const int wm   = (wave & 1) * 64;
    const int wn   = (wave >> 1) * 64;
    const int m0   = blockIdx.y * 128;
    const int n0   = blockIdx.x * 128;

    f32x4 acc[4][4];
#pragma unroll
    for (int i = 0; i < 4; i++)
#pragma unroll
        for (int j = 0; j < 4; j++)
#pragma unroll
            for (int r = 0; r < 4; r++) acc[i][j][r] = 0.f;

    for (int kt = 0; kt < K; kt += 64) {
        __syncthreads();
        // Stage A 128x64 fp32->bf16: 1024 vec8 chunks, 4/thread
#pragma unroll
        for (int i = 0; i < 4; i++) {
            int c = tid + 256 * i;
            int m = c >> 3, k8 = (c & 7) * 8;
            f32x8 a = *(const f32x8*)&Af[(size_t)(m0 + m) * K + kt + k8];
            bf16x8 h;
#pragma unroll
            for (int j = 0; j < 8; j++)
                h[j] = (short)__bfloat16_as_ushort(__float2bfloat16(a[j]));
            *(bf16x8*)&As[m][k8] = h;
        }
        // Stage W 64x128 transposed into Bs[n][k]
#pragma unroll
        for (int i = 0; i < 4; i++) {
            int c = tid + 256 * i;
            int n8 = (c & 15) * 8, k = c >> 4;
            f32x8 w = *(const f32x8*)&W[(size_t)(kt + k) * N + n0 + n8];
#pragma unroll
            for (int j = 0; j < 8; j++)
                Bs[n8 + j][k] = (short)__bfloat16_as_ushort(__float2bfloat16(w[j]));
        }
        __syncthreads();
#pragma unroll
        for (int ks = 0; ks < 2; ks++) {
            int kb = ks * 32 + (lane >> 4) * 8;
            bf16x8 af[4], bfr[4];
#pragma unroll
            for (int i = 0; i < 4; i++)
                af[i] = *(const bf16x8*)&As[wm + 16 * i + (lane & 15)][kb];
#pragma unroll
            for (int i = 0; i < 4; i++)
                bfr[i] = *(const bf16x8*)&Bs[wn + 16 * i + (lane & 15)][kb];
#pragma unroll
            for (int i = 0; i < 4; i++)
#pragma unroll
                for (int j = 0; j < 4; j++)
                    acc[i][j] = __builtin_amdgcn_mfma_f32_16x16x32_bf16(
                        af[i], bfr[j], acc[i][j], 0, 0, 0);
        }
    }

#pragma unroll
    for (int i = 0; i < 4; i++)
#pragma unroll
        for (int j = 0; j < 4; j++)
#pragma unroll
            for (int r = 0; r < 4; r++) {
                int m = m0 + wm + 16 * i + (lane >> 4) * 4 + r;
                int n = n0 + wn + 16 * j + (lane & 15);
                float v = acc[i][j][r];
                if (n < D_INNER)
                    outb0[(size_t)n * ML + m] = __float2bfloat16(v);
                else
                    outb1[(size_t)(n - D_INNER) * ML + m] =
                        __float2bfloat16(v / (1.f + __expf(-v)));
            }
}

// ---------------------------------------------------------------------------
// MFMA bf16 GEMM (R12-verbatim). C(MxN) = A(MxK) * W(KxN), W fp32 row-major.
// AMODE 1: A bf16 TRANSPOSED [K][M] (xp_t / y_t; stride M).
// EPI 1: outf = fp32 C row-major (ld=N, guard n<N)
// ---------------------------------------------------------------------------
template<int EPI, int AMODE>
__global__ __launch_bounds__(256)
void gemm_mfma(const float* __restrict__ Af, const bf16* __restrict__ At,
               const float* __restrict__ W,
               bf16* __restrict__ outb0, bf16* __restrict__ outb1,
               float* __restrict__ outf, int M, int N, int K)
{
    __shared__ __attribute__((aligned(16))) short As[64][72];
    __shared__ __attribute__((aligned(16))) short Bs[64][72];
    const int tid  = threadIdx.x;
    const int lane = tid & 63;
    const int wave = tid >> 6;
    const int wm   = (wave & 1) * 32;
    const int wn   = (wave >> 1) * 32;
    const int m0   = blockIdx.y * 64;
    const int n0   = blockIdx.x * 64;

    f32x4 acc[2][2];
#pragma unroll
    for (int i = 0; i < 2; i++)
#pragma unroll
        for (int j = 0; j < 2; j++)
#pragma unroll
            for (int r = 0; r < 4; r++) acc[i][j][r] = 0.f;

    for (int kt = 0; kt < K; kt += 64) {
        __syncthreads();
        // Stage A tile 64x64
#pragma unroll
        for (int i = 0; i < 2; i++) {
            int c = tid + 256 * i;
            if (AMODE == 0) {                    // fp32 row-major
                int m = c >> 3, k8 = (c & 7) * 8;
                f32x8 a = *(const f32x8*)&Af[(size_t)(m0 + m) * K + kt + k8];
                bf16x8 h;
#pragma unroll
                for (int j = 0; j < 8; j++)
                    h[j] = (short)__bfloat16_as_ushort(__float2bfloat16(a[j]));
                *(bf16x8*)&As[m][k8] = h;
            } else {                             // bf16 transposed [K][M]
                int m8 = (c & 7) * 8, k = c >> 3;
                bf16x8 a = *(const bf16x8*)&At[(size_t)(kt + k) * M + m0 + m8];
#pragma unroll
                for (int j = 0; j < 8; j++) As[m8 + j][k] = a[j];
            }
        }
        // Stage W tile 64x64 transposed into Bs[n][k], fp32 -> bf16
#pragma unroll
        for (int i = 0; i < 2; i++) {
            int c = tid + 256 * i;
            int n8 = (c & 7) * 8, k = c >> 3;
            if (n0 + n8 + 8 <= N) {
                f32x8 w = *(const f32x8*)&W[(size_t)(kt + k) * N + n0 + n8];
#pragma unroll
                for (int j = 0; j < 8; j++)
                    Bs[n8 + j][k] = (short)__bfloat16_as_ushort(__float2bfloat16(w[j]));
            } else {
#pragma unroll
                for (int j = 0; j < 8; j++) Bs[n8 + j][k] = 0;
            }
        }
        __syncthreads();
#pragma unroll
        for (int ks = 0; ks < 2; ks++) {
            int kb = ks * 32 + (lane >> 4) * 8;
            bf16x8 a0 = *(const bf16x8*)&As[wm + (lane & 15)][kb];
            bf16x8 a1 = *(const bf16x8*)&As[wm + 16 + (lane & 15)][kb];
            bf16x8 b0 = *(const bf16x8*)&Bs[wn + (lane & 15)][kb];
            bf16x8 b1 = *(const bf16x8*)&Bs[wn + 16 + (lane & 15)][kb];
            acc[0][0] = __builtin_amdgcn_mfma_f32_16x16x32_bf16(a0, b0, acc[0][0], 0, 0, 0);
            acc[0][1] = __builtin_amdgcn_mfma_f32_16x16x32_bf16(a0, b1, acc[0][1], 0, 0, 0);
            acc[1][0] = __builtin_amdgcn_mfma_f32_16x16x32_bf16(a1, b0, acc[1][0], 0, 0, 0);
            acc[1][1] = __builtin_amdgcn_mfma_f32_16x16x32_bf16(a1, b1, acc[1][1], 0, 0, 0);
        }
    }

#pragma unroll
    for (int am = 0; am < 2; am++)
#pragma unroll
        for (int bn = 0; bn < 2; bn++)
#pragma unroll
            for (int r = 0; r < 4; r++) {
                int m = m0 + wm + am * 16 + (lane >> 4) * 4 + r;
                int n = n0 + wn + bn * 16 + (lane & 15);
                float v = acc[am][bn][r];
                if (EPI == 0) {
                    if (n < D_INNER)
                        outb0[(size_t)n * ML + m] = __float2bfloat16(v);
                    else
                        outb1[(size_t)(n - D_INNER) * ML + m] =
                            __float2bfloat16(v / (1.f + __expf(-v)));
                } else {
                    if (n < N) outf[(size_t)m * N + n] = v;
                }
            }
}

// ---------------------------------------------------------------------------
// Causal depthwise conv (K=4) + bias + SiLU on TRANSPOSED layout [d][ml].
// (R12-verbatim)
// ---------------------------------------------------------------------------
__global__ __launch_bounds__(256)
void conv_silu_kernel(const bf16* __restrict__ xp_raw_t,
                      const float* __restrict__ cw, const float* __restrict__ cb,
                      bf16* __restrict__ xp_t)
{
    const int ml = blockIdx.x * 256 + threadIdx.x;
    const int d  = blockIdx.y;
    const int l  = ml & (L_SEQ - 1);
    const size_t row = (size_t)d * ML;
    float s = cb[d];
#pragma unroll
    for (int j = 0; j < 4; j++) {
        if (l - 3 + j >= 0)
            s += __bfloat162float(xp_raw_t[row + ml - 3 + j]) * cw[d * 4 + j];
    }
    float act = s / (1.f + __expf(-s));                 // silu
    xp_t[row + ml] = __float2bfloat16(act);
}

// ---------------------------------------------------------------------------
// dt = softplus(dt_r @ dt_proj_w + b), LDS-tiled: block = 64 m x 48 d.
// Replaces the (ML/256, 768) grid whose per-d blocks re-read x_dbl 768x
// (~300 MB L2 traffic). x-tile 64x24 (+1 pad -> conflict-free), w-tile 24x48.
// Per wave: dd uniform (ws broadcast), mloc = lane (xs conflict-free,
// stores 128B contiguous).
// ---------------------------------------------------------------------------
__global__ __launch_bounds__(256)
void dt_kernel(const float* __restrict__ x_dbl, const float* __restrict__ dtw,
               const float* __restrict__ dtb, bf16* __restrict__ dt_t)
{
    __shared__ float xs[64 * 25];
    __shared__ float ws[24 * 48];
    const int tid = threadIdx.x;
    const int m0 = blockIdx.x * 64;
    const int d0 = blockIdx.y * 48;
#pragma unroll
    for (int i = 0; i < 6; i++) {
        int idx = tid + 256 * i;        // < 1536 = 64*24
        int r_ = idx / 24, cc = idx % 24;
        xs[r_ * 25 + cc] = x_dbl[(size_t)(m0 + r_) * 56 + cc];
    }
#pragma unroll
    for (int i = 0; i < 5; i++) {
        int idx = tid + 256 * i;
        if (idx < 24 * 48) {
            int r_ = idx / 48, dd = idx % 48;
            ws[idx] = dtw[r_ * D_INNER + d0 + dd];
        }
    }
    __syncthreads();
#pragma unroll
    for (int i = 0; i < 12; i++) {
        int o = tid + 256 * i;          // < 3072 = 64*48
        int mloc = o & 63, dd = o >> 6; // dd wave-uniform
        float acc = dtb[d0 + dd];
#pragma unroll
        for (int r_ = 0; r_ < 24; r_++)
            acc += xs[mloc * 25 + r_] * ws[r_ * 48 + dd];
        float sp = fmaxf(acc, 0.f) + log1pf(__expf(-fabsf(acc)));
        dt_t[(size_t)(d0 + dd) * ML + m0 + mloc] = __float2bfloat16(sp);
    }
}

// ---------------------------------------------------------------------------
// Chunk-parallel selective scan (R12-verbatim, green).
// One 1024-thr block per (b,d); thread = (chunk c=tid>>4, state n=tid&15).
// ---------------------------------------------------------------------------
__global__ __launch_bounds__(1024)
void scan_kernel(const bf16* __restrict__ dt_t, const bf16* __restrict__ xp_t,
                 const float* __restrict__ x_dbl, const bf16* __restrict__ zs_t,
                 const float* __restrict__ A_log, const float* __restrict__ Dp,
                 bf16* __restrict__ y_t)
{
    __shared__ float sP[NCHUNK][D_STATE];
    __shared__ float sH[NCHUNK][D_STATE];
    const int tid = threadIdx.x;
    const int c = tid >> 4;           // chunk 0..63
    const int n = tid & 15;           // state 0..15
    const int g = blockIdx.x;         // (b,d)
    const int b = g / D_INNER;
    const int d = g % D_INNER;
    const float A = -__expf(A_log[d * D_STATE + n]);
    const size_t base_t = (size_t)d * ML + (size_t)b * L_SEQ + (size_t)c * CHLEN;
    const size_t base_m = (size_t)b * L_SEQ + (size_t)c * CHLEN;

    float h = 0.f, P = 1.f;
#pragma unroll 4
    for (int j = 0; j < CHLEN; j++) {
        float dtv = __bfloat162float(dt_t[base_t + j]);
        float xpv = __bfloat162float(xp_t[base_t + j]);
        float Bn  = x_dbl[(base_m + j) * 56 + DT_RANK + n];
        float aj = __expf(dtv * A);
        float uj = Bn * (dtv * xpv);
        h = aj * h + uj;
        P *= aj;
    }
    sP[c][n] = P;
    sH[c][n] = h;
    __syncthreads();

    // Kogge-Stone inclusive scan over chunks: compose (P,h) pairs
#pragma unroll
    for (int s = 1; s < NCHUNK; s <<= 1) {
        float p2 = 0.f, h2 = 0.f;
        const bool act = (c >= s);
        if (act) { p2 = sP[c - s][n]; h2 = sH[c - s][n]; }
        __syncthreads();
        if (act) {
            sH[c][n] = sP[c][n] * h2 + sH[c][n];
            sP[c][n] = sP[c][n] * p2;
        }
        __syncthreads();
    }
    const float hinit = (c == 0) ? 0.f : sH[c - 1][n];

    // Phase 3: corrected re-scan (recompute a,u) + output
    const float Dd = Dp[d];
    h = hinit;
#pragma unroll 4
    for (int j = 0; j < CHLEN; j++) {
        float dtv = __bfloat162float(dt_t[base_t + j]);
        float xpv = __bfloat162float(xp_t[base_t + j]);
        float Bn  = x_dbl[(base_m + j) * 56 + DT_RANK + n];
        float aj = __expf(dtv * A);
        float uj = Bn * (dtv * xpv);
        h = aj * h + uj;
        float Cn = x_dbl[(base_m + j) * 56 + DT_RANK + D_STATE + n];
        float yv = h * Cn;
        yv += __shfl_xor(yv, 1);
        yv += __shfl_xor(yv, 2);
        yv += __shfl_xor(yv, 4);
        yv += __shfl_xor(yv, 8);
        if (n == 0) {
            float y = (yv + xpv * Dd) * __bfloat162float(zs_t[base_t + j]);
            y_t[base_t + j] = __float2bfloat16(y);
        }
    }
}

// ---------------------------------------------------------------------------
extern "C" void kernel_launch(void* const* d_in, const int* in_sizes, int n_in,
                              void* d_out, int out_size, void* d_ws, size_t ws_size,
                              hipStream_t stream)
{
    const float* x         = (const float*)d_in[0];
    const float* in_proj_w = (const float*)d_in[1];
    const float* conv_w    = (const float*)d_in[2];
    const float* conv_b    = (const float*)d_in[3];
    const float* x_proj_w  = (const float*)d_in[4];
    const float* dt_proj_w = (const float*)d_in[5];
    const float* dt_proj_b = (const float*)d_in[6];
    const float* A_log     = (const float*)d_in[7];
    const float* Dvec      = (const float*)d_in[8];
    const float* out_proj_w= (const float*)d_in[9];

    // workspace (all transposed [d][ml] bf16 except x_dbl): ~26.1 MB
    bf16* xp_raw_t = (bf16*)d_ws;                        // [768][ML] (reused as y_t)
    bf16* zs_t     = xp_raw_t + (size_t)ML * D_INNER;    // [768][ML] silu(z)
    bf16* xp_t     = zs_t     + (size_t)ML * D_INNER;    // [768][ML]
    bf16* dt_t     = xp_t     + (size_t)ML * D_INNER;    // [768][ML]
    float* x_dbl   = (float*)(dt_t + (size_t)ML * D_INNER); // [ML][56] fp32
    bf16* y_t      = xp_raw_t;                           // alias (dead after conv)

    dim3 blk(256);

    // 1) in_proj (128x128 tile): -> xp_raw_t | zs_t (transposed)
    gemm_inproj_128<<<dim3(2 * D_INNER / 128, ML / 128), blk, 0, stream>>>(
        x, in_proj_w, xp_raw_t, zs_t, ML, 2 * D_INNER, D_MODEL);

    // 2) depthwise causal conv + silu (contiguous stencil in [d][ml])
    conv_silu_kernel<<<dim3(ML / 256, D_INNER), blk, 0, stream>>>(
        xp_raw_t, conv_w, conv_b, xp_t);

    // 3) x_proj: A = xp_t (transposed), W (768x56) -> x_dbl fp32 row-major
    gemm_mfma<1, 1><<<dim3(1, ML / 64), blk, 0, stream>>>(
        nullptr, xp_t, x_proj_w, nullptr, nullptr, x_dbl, ML, 56, D_INNER);

    // 4) dt_proj + softplus (LDS-tiled) -> dt_t (transposed)
    dt_kernel<<<dim3(ML / 64, D_INNER / 48), blk, 0, stream>>>(
        x_dbl, dt_proj_w, dt_proj_b, dt_t);

    // 5) chunk-parallel selective scan -> y_t (transposed, aliases xp_raw_t)
    scan_kernel<<<B_SZ * D_INNER, 1024, 0, stream>>>(
        dt_t, xp_t, x_dbl, zs_t, A_log, Dvec, y_t);

    // 6) out_proj: A = y_t (transposed), W (768x384) -> d_out fp32 row-major
    gemm_mfma<1, 1><<<dim3(D_MODEL / 64, ML / 64), blk, 0, stream>>>(
        nullptr, y_t, out_proj_w, nullptr, nullptr, (float*)d_out, ML, D_MODEL, D_INNER);
}

// Round 14
// 263.571 us; speedup vs baseline: 1.0827x; 1.0827x over previous
//
#include <hip/hip_runtime.h>
#include <hip/hip_bf16.h>

#define B_SZ    2
#define L_SEQ   2048
#define D_MODEL 384
#define D_INNER 768
#define D_STATE 16
#define DT_RANK 24
#define ML      (B_SZ * L_SEQ)   // 4096 rows
#define NCHUNK  64
#define CHLEN   (L_SEQ / NCHUNK) // 32

typedef __hip_bfloat16 bf16;
typedef __attribute__((ext_vector_type(8))) short bf16x8;
typedef __attribute__((ext_vector_type(4))) float f32x4;
typedef __attribute__((ext_vector_type(8))) float f32x8;

// ---------------------------------------------------------------------------
// MFMA bf16 GEMM (R12-verbatim, green). C(MxN) = A(MxK) * W(KxN), W fp32.
// AMODE 0: A fp32 row-major [M][K] (in_proj).  AMODE 1: A bf16 transposed [K][M].
// 256 thr / 4 waves; tile 64x64, BK=64; wave = 32x32 via 2x2 16x16x32 MFMA.
// EPI 0: in_proj split, transposed: outb0[n][m]=xp_raw, outb1[n-768][m]=silu(z)
// EPI 1: outf = fp32 C row-major (ld=N, guard n<N)
// ---------------------------------------------------------------------------
template<int EPI, int AMODE>
__global__ __launch_bounds__(256)
void gemm_mfma(const float* __restrict__ Af, const bf16* __restrict__ At,
               const float* __restrict__ W,
               bf16* __restrict__ outb0, bf16* __restrict__ outb1,
               float* __restrict__ outf, int M, int N, int K)
{
    __shared__ __attribute__((aligned(16))) short As[64][72];
    __shared__ __attribute__((aligned(16))) short Bs[64][72];
    const int tid  = threadIdx.x;
    const int lane = tid & 63;
    const int wave = tid >> 6;
    const int wm   = (wave & 1) * 32;
    const int wn   = (wave >> 1) * 32;
    const int m0   = blockIdx.y * 64;
    const int n0   = blockIdx.x * 64;

    f32x4 acc[2][2];
#pragma unroll
    for (int i = 0; i < 2; i++)
#pragma unroll
        for (int j = 0; j < 2; j++)
#pragma unroll
            for (int r = 0; r < 4; r++) acc[i][j][r] = 0.f;

    for (int kt = 0; kt < K; kt += 64) {
        __syncthreads();
        // Stage A tile 64x64
#pragma unroll
        for (int i = 0; i < 2; i++) {
            int c = tid + 256 * i;
            if (AMODE == 0) {                    // fp32 row-major
                int m = c >> 3, k8 = (c & 7) * 8;
                f32x8 a = *(const f32x8*)&Af[(size_t)(m0 + m) * K + kt + k8];
                bf16x8 h;
#pragma unroll
                for (int j = 0; j < 8; j++)
                    h[j] = (short)__bfloat16_as_ushort(__float2bfloat16(a[j]));
                *(bf16x8*)&As[m][k8] = h;
            } else {                             // bf16 transposed [K][M]
                int m8 = (c & 7) * 8, k = c >> 3;
                bf16x8 a = *(const bf16x8*)&At[(size_t)(kt + k) * M + m0 + m8];
#pragma unroll
                for (int j = 0; j < 8; j++) As[m8 + j][k] = a[j];
            }
        }
        // Stage W tile 64x64 transposed into Bs[n][k], fp32 -> bf16
#pragma unroll
        for (int i = 0; i < 2; i++) {
            int c = tid + 256 * i;
            int n8 = (c & 7) * 8, k = c >> 3;
            if (n0 + n8 + 8 <= N) {
                f32x8 w = *(const f32x8*)&W[(size_t)(kt + k) * N + n0 + n8];
#pragma unroll
                for (int j = 0; j < 8; j++)
                    Bs[n8 + j][k] = (short)__bfloat16_as_ushort(__float2bfloat16(w[j]));
            } else {
#pragma unroll
                for (int j = 0; j < 8; j++) Bs[n8 + j][k] = 0;
            }
        }
        __syncthreads();
#pragma unroll
        for (int ks = 0; ks < 2; ks++) {
            int kb = ks * 32 + (lane >> 4) * 8;
            bf16x8 a0 = *(const bf16x8*)&As[wm + (lane & 15)][kb];
            bf16x8 a1 = *(const bf16x8*)&As[wm + 16 + (lane & 15)][kb];
            bf16x8 b0 = *(const bf16x8*)&Bs[wn + (lane & 15)][kb];
            bf16x8 b1 = *(const bf16x8*)&Bs[wn + 16 + (lane & 15)][kb];
            acc[0][0] = __builtin_amdgcn_mfma_f32_16x16x32_bf16(a0, b0, acc[0][0], 0, 0, 0);
            acc[0][1] = __builtin_amdgcn_mfma_f32_16x16x32_bf16(a0, b1, acc[0][1], 0, 0, 0);
            acc[1][0] = __builtin_amdgcn_mfma_f32_16x16x32_bf16(a1, b0, acc[1][0], 0, 0, 0);
            acc[1][1] = __builtin_amdgcn_mfma_f32_16x16x32_bf16(a1, b1, acc[1][1], 0, 0, 0);
        }
    }

#pragma unroll
    for (int am = 0; am < 2; am++)
#pragma unroll
        for (int bn = 0; bn < 2; bn++)
#pragma unroll
            for (int r = 0; r < 4; r++) {
                int m = m0 + wm + am * 16 + (lane >> 4) * 4 + r;
                int n = n0 + wn + bn * 16 + (lane & 15);
                float v = acc[am][bn][r];
                if (EPI == 0) {
                    if (n < D_INNER)
                        outb0[(size_t)n * ML + m] = __float2bfloat16(v);
                    else
                        outb1[(size_t)(n - D_INNER) * ML + m] =
                            __float2bfloat16(v / (1.f + __expf(-v)));
                } else {
                    if (n < N) outf[(size_t)m * N + n] = v;
                }
            }
}

// ---------------------------------------------------------------------------
// x_proj GEMM with K-split x4: grid (4, ML/64). Block (kc, my) computes the
// partial over K in [kc*192, kc*192+192) for a 64-row M-tile, atomicAdd fp32
// into x_dbl (zeroed via hipMemsetAsync). Fixes the (1,64)-grid version's
// 1-wave/CU latency exposure (12 serial staged K-iters, no TLP).
// ---------------------------------------------------------------------------
__global__ __launch_bounds__(256)
void gemm_xproj_split(const bf16* __restrict__ At, const float* __restrict__ W,
                      float* __restrict__ outf, int M, int N, int K)
{
    __shared__ __attribute__((aligned(16))) short As[64][72];
    __shared__ __attribute__((aligned(16))) short Bs[64][72];
    const int tid  = threadIdx.x;
    const int lane = tid & 63;
    const int wave = tid >> 6;
    const int wm   = (wave & 1) * 32;
    const int wn   = (wave >> 1) * 32;
    const int m0   = blockIdx.y * 64;
    const int k0   = blockIdx.x * (768 / 4);     // 192-wide K chunk

    f32x4 acc[2][2];
#pragma unroll
    for (int i = 0; i < 2; i++)
#pragma unroll
        for (int j = 0; j < 2; j++)
#pragma unroll
            for (int r = 0; r < 4; r++) acc[i][j][r] = 0.f;

    for (int kt = k0; kt < k0 + 192; kt += 64) {
        __syncthreads();
#pragma unroll
        for (int i = 0; i < 2; i++) {
            int c = tid + 256 * i;
            int m8 = (c & 7) * 8, k = c >> 3;
            bf16x8 a = *(const bf16x8*)&At[(size_t)(kt + k) * M + m0 + m8];
#pragma unroll
            for (int j = 0; j < 8; j++) As[m8 + j][k] = a[j];
        }
#pragma unroll
        for (int i = 0; i < 2; i++) {
            int c = tid + 256 * i;
            int n8 = (c & 7) * 8, k = c >> 3;
            if (n8 + 8 <= N) {
                f32x8 w = *(const f32x8*)&W[(size_t)(kt + k) * N + n8];
#pragma unroll
                for (int j = 0; j < 8; j++)
                    Bs[n8 + j][k] = (short)__bfloat16_as_ushort(__float2bfloat16(w[j]));
            } else {
#pragma unroll
                for (int j = 0; j < 8; j++) Bs[n8 + j][k] = 0;
            }
        }
        __syncthreads();
#pragma unroll
        for (int ks = 0; ks < 2; ks++) {
            int kb = ks * 32 + (lane >> 4) * 8;
            bf16x8 a0 = *(const bf16x8*)&As[wm + (lane & 15)][kb];
            bf16x8 a1 = *(const bf16x8*)&As[wm + 16 + (lane & 15)][kb];
            bf16x8 b0 = *(const bf16x8*)&Bs[wn + (lane & 15)][kb];
            bf16x8 b1 = *(const bf16x8*)&Bs[wn + 16 + (lane & 15)][kb];
            acc[0][0] = __builtin_amdgcn_mfma_f32_16x16x32_bf16(a0, b0, acc[0][0], 0, 0, 0);
            acc[0][1] = __builtin_amdgcn_mfma_f32_16x16x32_bf16(a0, b1, acc[0][1], 0, 0, 0);
            acc[1][0] = __builtin_amdgcn_mfma_f32_16x16x32_bf16(a1, b0, acc[1][0], 0, 0, 0);
            acc[1][1] = __builtin_amdgcn_mfma_f32_16x16x32_bf16(a1, b1, acc[1][1], 0, 0, 0);
        }
    }

#pragma unroll
    for (int am = 0; am < 2; am++)
#pragma unroll
        for (int bn = 0; bn < 2; bn++)
#pragma unroll
            for (int r = 0; r < 4; r++) {
                int m = m0 + wm + am * 16 + (lane >> 4) * 4 + r;
                int n = wn + bn * 16 + (lane & 15);
                if (n < N)
                    atomicAdd(&outf[(size_t)m * N + n], acc[am][bn][r]);
            }
}

// ---------------------------------------------------------------------------
// Causal depthwise conv (K=4) + bias + SiLU on [d][ml]. (R12-verbatim)
// ---------------------------------------------------------------------------
__global__ __launch_bounds__(256)
void conv_silu_kernel(const bf16* __restrict__ xp_raw_t,
                      const float* __restrict__ cw, const float* __restrict__ cb,
                      bf16* __restrict__ xp_t)
{
    const int ml = blockIdx.x * 256 + threadIdx.x;
    const int d  = blockIdx.y;
    const int l  = ml & (L_SEQ - 1);
    const size_t row = (size_t)d * ML;
    float s = cb[d];
#pragma unroll
    for (int j = 0; j < 4; j++) {
        if (l - 3 + j >= 0)
            s += __bfloat162float(xp_raw_t[row + ml - 3 + j]) * cw[d * 4 + j];
    }
    float act = s / (1.f + __expf(-s));                 // silu
    xp_t[row + ml] = __float2bfloat16(act);
}

// ---------------------------------------------------------------------------
// dt = softplus(dt_r @ dt_proj_w + b), LDS-tiled (R13-green): 64 m x 48 d.
// ---------------------------------------------------------------------------
__global__ __launch_bounds__(256)
void dt_kernel(const float* __restrict__ x_dbl, const float* __restrict__ dtw,
               const float* __restrict__ dtb, bf16* __restrict__ dt_t)
{
    __shared__ float xs[64 * 25];
    __shared__ float ws[24 * 48];
    const int tid = threadIdx.x;
    const int m0 = blockIdx.x * 64;
    const int d0 = blockIdx.y * 48;
#pragma unroll
    for (int i = 0; i < 6; i++) {
        int idx = tid + 256 * i;        // < 1536 = 64*24
        int r_ = idx / 24, cc = idx % 24;
        xs[r_ * 25 + cc] = x_dbl[(size_t)(m0 + r_) * 56 + cc];
    }
#pragma unroll
    for (int i = 0; i < 5; i++) {
        int idx = tid + 256 * i;
        if (idx < 24 * 48) {
            int r_ = idx / 48, dd = idx % 48;
            ws[idx] = dtw[r_ * D_INNER + d0 + dd];
        }
    }
    __syncthreads();
#pragma unroll
    for (int i = 0; i < 12; i++) {
        int o = tid + 256 * i;          // < 3072 = 64*48
        int mloc = o & 63, dd = o >> 6; // dd wave-uniform
        float acc = dtb[d0 + dd];
#pragma unroll
        for (int r_ = 0; r_ < 24; r_++)
            acc += xs[mloc * 25 + r_] * ws[r_ * 48 + dd];
        float sp = fmaxf(acc, 0.f) + log1pf(__expf(-fabsf(acc)));
        dt_t[(size_t)(d0 + dd) * ML + m0 + mloc] = __float2bfloat16(sp);
    }
}

// ---------------------------------------------------------------------------
// Chunk-parallel selective scan (R12-verbatim, green).
// ---------------------------------------------------------------------------
__global__ __launch_bounds__(1024)
void scan_kernel(const bf16* __restrict__ dt_t, const bf16* __restrict__ xp_t,
                 const float* __restrict__ x_dbl, const bf16* __restrict__ zs_t,
                 const float* __restrict__ A_log, const float* __restrict__ Dp,
                 bf16* __restrict__ y_t)
{
    __shared__ float sP[NCHUNK][D_STATE];
    __shared__ float sH[NCHUNK][D_STATE];
    const int tid = threadIdx.x;
    const int c = tid >> 4;           // chunk 0..63
    const int n = tid & 15;           // state 0..15
    const int g = blockIdx.x;         // (b,d)
    const int b = g / D_INNER;
    const int d = g % D_INNER;
    const float A = -__expf(A_log[d * D_STATE + n]);
    const size_t base_t = (size_t)d * ML + (size_t)b * L_SEQ + (size_t)c * CHLEN;
    const size_t base_m = (size_t)b * L_SEQ + (size_t)c * CHLEN;

    float h = 0.f, P = 1.f;
#pragma unroll 4
    for (int j = 0; j < CHLEN; j++) {
        float dtv = __bfloat162float(dt_t[base_t + j]);
        float xpv = __bfloat162float(xp_t[base_t + j]);
        float Bn  = x_dbl[(base_m + j) * 56 + DT_RANK + n];
        float aj = __expf(dtv * A);
        float uj = Bn * (dtv * xpv);
        h = aj * h + uj;
        P *= aj;
    }
    sP[c][n] = P;
    sH[c][n] = h;
    __syncthreads();

    // Kogge-Stone inclusive scan over chunks: compose (P,h) pairs
#pragma unroll
    for (int s = 1; s < NCHUNK; s <<= 1) {
        float p2 = 0.f, h2 = 0.f;
        const bool act = (c >= s);
        if (act) { p2 = sP[c - s][n]; h2 = sH[c - s][n]; }
        __syncthreads();
        if (act) {
            sH[c][n] = sP[c][n] * h2 + sH[c][n];
            sP[c][n] = sP[c][n] * p2;
        }
        __syncthreads();
    }
    const float hinit = (c == 0) ? 0.f : sH[c - 1][n];

    // Phase 3: corrected re-scan (recompute a,u) + output
    const float Dd = Dp[d];
    h = hinit;
#pragma unroll 4
    for (int j = 0; j < CHLEN; j++) {
        float dtv = __bfloat162float(dt_t[base_t + j]);
        float xpv = __bfloat162float(xp_t[base_t + j]);
        float Bn  = x_dbl[(base_m + j) * 56 + DT_RANK + n];
        float aj = __expf(dtv * A);
        float uj = Bn * (dtv * xpv);
        h = aj * h + uj;
        float Cn = x_dbl[(base_m + j) * 56 + DT_RANK + D_STATE + n];
        float yv = h * Cn;
        yv += __shfl_xor(yv, 1);
        yv += __shfl_xor(yv, 2);
        yv += __shfl_xor(yv, 4);
        yv += __shfl_xor(yv, 8);
        if (n == 0) {
            float y = (yv + xpv * Dd) * __bfloat162float(zs_t[base_t + j]);
            y_t[base_t + j] = __float2bfloat16(y);
        }
    }
}

// ---------------------------------------------------------------------------
extern "C" void kernel_launch(void* const* d_in, const int* in_sizes, int n_in,
                              void* d_out, int out_size, void* d_ws, size_t ws_size,
                              hipStream_t stream)
{
    const float* x         = (const float*)d_in[0];
    const float* in_proj_w = (const float*)d_in[1];
    const float* conv_w    = (const float*)d_in[2];
    const float* conv_b    = (const float*)d_in[3];
    const float* x_proj_w  = (const float*)d_in[4];
    const float* dt_proj_w = (const float*)d_in[5];
    const float* dt_proj_b = (const float*)d_in[6];
    const float* A_log     = (const float*)d_in[7];
    const float* Dvec      = (const float*)d_in[8];
    const float* out_proj_w= (const float*)d_in[9];

    // workspace (all transposed [d][ml] bf16 except x_dbl): ~26.1 MB
    bf16* xp_raw_t = (bf16*)d_ws;                        // [768][ML] (reused as y_t)
    bf16* zs_t     = xp_raw_t + (size_t)ML * D_INNER;    // [768][ML] silu(z)
    bf16* xp_t     = zs_t     + (size_t)ML * D_INNER;    // [768][ML]
    bf16* dt_t     = xp_t     + (size_t)ML * D_INNER;    // [768][ML]
    float* x_dbl   = (float*)(dt_t + (size_t)ML * D_INNER); // [ML][56] fp32
    bf16* y_t      = xp_raw_t;                           // alias (dead after conv)

    dim3 blk(256);

    // 1) in_proj (64x64, R12-proven): -> xp_raw_t | zs_t (transposed)
    gemm_mfma<0, 0><<<dim3(2 * D_INNER / 64, ML / 64), blk, 0, stream>>>(
        x, nullptr, in_proj_w, xp_raw_t, zs_t, nullptr, ML, 2 * D_INNER, D_MODEL);

    // 2) depthwise causal conv + silu
    conv_silu_kernel<<<dim3(ML / 256, D_INNER), blk, 0, stream>>>(
        xp_raw_t, conv_w, conv_b, xp_t);

    // 3) x_proj, K-split x4 with fp32 atomics (x_dbl zeroed first)
    hipMemsetAsync(x_dbl, 0, (size_t)ML * 56 * sizeof(float), stream);
    gemm_xproj_split<<<dim3(4, ML / 64), blk, 0, stream>>>(
        xp_t, x_proj_w, x_dbl, ML, 56, D_INNER);

    // 4) dt_proj + softplus (LDS-tiled, R13-green) -> dt_t
    dt_kernel<<<dim3(ML / 64, D_INNER / 48), blk, 0, stream>>>(
        x_dbl, dt_proj_w, dt_proj_b, dt_t);

    // 5) chunk-parallel selective scan -> y_t (aliases xp_raw_t)
    scan_kernel<<<B_SZ * D_INNER, 1024, 0, stream>>>(
        dt_t, xp_t, x_dbl, zs_t, A_log, Dvec, y_t);

    // 6) out_proj: A = y_t (transposed), W (768x384) -> d_out fp32
    gemm_mfma<1, 1><<<dim3(D_MODEL / 64, ML / 64), blk, 0, stream>>>(
        nullptr, y_t, out_proj_w, nullptr, nullptr, (float*)d_out, ML, D_MODEL, D_INNER);
}

// Round 16
// 258.684 us; speedup vs baseline: 1.1031x; 1.0189x over previous
//
#include <hip/hip_runtime.h>
#include <hip/hip_bf16.h>

#define B_SZ    2
#define L_SEQ   2048
#define D_MODEL 384
#define D_INNER 768
#define D_STATE 16
#define DT_RANK 24
#define ML      (B_SZ * L_SEQ)   // 4096 rows
#define NCHUNK  64
#define CHLEN   (L_SEQ / NCHUNK) // 32

typedef __hip_bfloat16 bf16;
typedef __attribute__((ext_vector_type(8))) short bf16x8;
typedef __attribute__((ext_vector_type(4))) float f32x4;
typedef __attribute__((ext_vector_type(8))) float f32x8;

// ---------------------------------------------------------------------------
// MFMA bf16 GEMM (R12/R14-verbatim, green). C(MxN) = A(MxK) * W(KxN), W fp32.
// AMODE 0: A fp32 row-major [M][K] (in_proj).  AMODE 1: A bf16 transposed [K][M].
// 256 thr / 4 waves; tile 64x64, BK=64; wave = 32x32 via 2x2 16x16x32 MFMA.
// EPI 0: in_proj split, transposed: outb0[n][m]=xp_raw, outb1[n-768][m]=silu(z)
// EPI 1: outf = fp32 C row-major (ld=N, guard n<N)
// ---------------------------------------------------------------------------
template<int EPI, int AMODE>
__global__ __launch_bounds__(256)
void gemm_mfma(const float* __restrict__ Af, const bf16* __restrict__ At,
               const float* __restrict__ W,
               bf16* __restrict__ outb0, bf16* __restrict__ outb1,
               float* __restrict__ outf, int M, int N, int K)
{
    __shared__ __attribute__((aligned(16))) short As[64][72];
    __shared__ __attribute__((aligned(16))) short Bs[64][72];
    const int tid  = threadIdx.x;
    const int lane = tid & 63;
    const int wave = tid >> 6;
    const int wm   = (wave & 1) * 32;
    const int wn   = (wave >> 1) * 32;
    const int m0   = blockIdx.y * 64;
    const int n0   = blockIdx.x * 64;

    f32x4 acc[2][2];
#pragma unroll
    for (int i = 0; i < 2; i++)
#pragma unroll
        for (int j = 0; j < 2; j++)
#pragma unroll
            for (int r = 0; r < 4; r++) acc[i][j][r] = 0.f;

    for (int kt = 0; kt < K; kt += 64) {
        __syncthreads();
        // Stage A tile 64x64
#pragma unroll
        for (int i = 0; i < 2; i++) {
            int c = tid + 256 * i;
            if (AMODE == 0) {                    // fp32 row-major
                int m = c >> 3, k8 = (c & 7) * 8;
                f32x8 a = *(const f32x8*)&Af[(size_t)(m0 + m) * K + kt + k8];
                bf16x8 h;
#pragma unroll
                for (int j = 0; j < 8; j++)
                    h[j] = (short)__bfloat16_as_ushort(__float2bfloat16(a[j]));
                *(bf16x8*)&As[m][k8] = h;
            } else {                             // bf16 transposed [K][M]
                int m8 = (c & 7) * 8, k = c >> 3;
                bf16x8 a = *(const bf16x8*)&At[(size_t)(kt + k) * M + m0 + m8];
#pragma unroll
                for (int j = 0; j < 8; j++) As[m8 + j][k] = a[j];
            }
        }
        // Stage W tile 64x64 transposed into Bs[n][k], fp32 -> bf16
#pragma unroll
        for (int i = 0; i < 2; i++) {
            int c = tid + 256 * i;
            int n8 = (c & 7) * 8, k = c >> 3;
            if (n0 + n8 + 8 <= N) {
                f32x8 w = *(const f32x8*)&W[(size_t)(kt + k) * N + n0 + n8];
#pragma unroll
                for (int j = 0; j < 8; j++)
                    Bs[n8 + j][k] = (short)__bfloat16_as_ushort(__float2bfloat16(w[j]));
            } else {
#pragma unroll
                for (int j = 0; j < 8; j++) Bs[n8 + j][k] = 0;
            }
        }
        __syncthreads();
#pragma unroll
        for (int ks = 0; ks < 2; ks++) {
            int kb = ks * 32 + (lane >> 4) * 8;
            bf16x8 a0 = *(const bf16x8*)&As[wm + (lane & 15)][kb];
            bf16x8 a1 = *(const bf16x8*)&As[wm + 16 + (lane & 15)][kb];
            bf16x8 b0 = *(const bf16x8*)&Bs[wn + (lane & 15)][kb];
            bf16x8 b1 = *(const bf16x8*)&Bs[wn + 16 + (lane & 15)][kb];
            acc[0][0] = __builtin_amdgcn_mfma_f32_16x16x32_bf16(a0, b0, acc[0][0], 0, 0, 0);
            acc[0][1] = __builtin_amdgcn_mfma_f32_16x16x32_bf16(a0, b1, acc[0][1], 0, 0, 0);
            acc[1][0] = __builtin_amdgcn_mfma_f32_16x16x32_bf16(a1, b0, acc[1][0], 0, 0, 0);
            acc[1][1] = __builtin_amdgcn_mfma_f32_16x16x32_bf16(a1, b1, acc[1][1], 0, 0, 0);
        }
    }

#pragma unroll
    for (int am = 0; am < 2; am++)
#pragma unroll
        for (int bn = 0; bn < 2; bn++)
#pragma unroll
            for (int r = 0; r < 4; r++) {
                int m = m0 + wm + am * 16 + (lane >> 4) * 4 + r;
                int n = n0 + wn + bn * 16 + (lane & 15);
                float v = acc[am][bn][r];
                if (EPI == 0) {
                    if (n < D_INNER)
                        outb0[(size_t)n * ML + m] = __float2bfloat16(v);
                    else
                        outb1[(size_t)(n - D_INNER) * ML + m] =
                            __float2bfloat16(v / (1.f + __expf(-v)));
                } else {
                    if (n < N) outf[(size_t)m * N + n] = v;
                }
            }
}

// ---------------------------------------------------------------------------
// x_proj GEMM with K-split x4 (R14-verbatim, green): grid (4, ML/64).
// Partial over K in [kc*192, kc*192+192), atomicAdd fp32 into x_dbl.
// ---------------------------------------------------------------------------
__global__ __launch_bounds__(256)
void gemm_xproj_split(const bf16* __restrict__ At, const float* __restrict__ W,
                      float* __restrict__ outf, int M, int N, int K)
{
    __shared__ __attribute__((aligned(16))) short As[64][72];
    __shared__ __attribute__((aligned(16))) short Bs[64][72];
    const int tid  = threadIdx.x;
    const int lane = tid & 63;
    const int wave = tid >> 6;
    const int wm   = (wave & 1) * 32;
    const int wn   = (wave >> 1) * 32;
    const int m0   = blockIdx.y * 64;
    const int k0   = blockIdx.x * (768 / 4);     // 192-wide K chunk

    f32x4 acc[2][2];
#pragma unroll
    for (int i = 0; i < 2; i++)
#pragma unroll
        for (int j = 0; j < 2; j++)
#pragma unroll
            for (int r = 0; r < 4; r++) acc[i][j][r] = 0.f;

    for (int kt = k0; kt < k0 + 192; kt += 64) {
        __syncthreads();
#pragma unroll
        for (int i = 0; i < 2; i++) {
            int c = tid + 256 * i;
            int m8 = (c & 7) * 8, k = c >> 3;
            bf16x8 a = *(const bf16x8*)&At[(size_t)(kt + k) * M + m0 + m8];
#pragma unroll
            for (int j = 0; j < 8; j++) As[m8 + j][k] = a[j];
        }
#pragma unroll
        for (int i = 0; i < 2; i++) {
            int c = tid + 256 * i;
            int n8 = (c & 7) * 8, k = c >> 3;
            if (n8 + 8 <= N) {
                f32x8 w = *(const f32x8*)&W[(size_t)(kt + k) * N + n8];
#pragma unroll
                for (int j = 0; j < 8; j++)
                    Bs[n8 + j][k] = (short)__bfloat16_as_ushort(__float2bfloat16(w[j]));
            } else {
#pragma unroll
                for (int j = 0; j < 8; j++) Bs[n8 + j][k] = 0;
            }
        }
        __syncthreads();
#pragma unroll
        for (int ks = 0; ks < 2; ks++) {
            int kb = ks * 32 + (lane >> 4) * 8;
            bf16x8 a0 = *(const bf16x8*)&As[wm + (lane & 15)][kb];
            bf16x8 a1 = *(const bf16x8*)&As[wm + 16 + (lane & 15)][kb];
            bf16x8 b0 = *(const bf16x8*)&Bs[wn + (lane & 15)][kb];
            bf16x8 b1 = *(const bf16x8*)&Bs[wn + 16 + (lane & 15)][kb];
            acc[0][0] = __builtin_amdgcn_mfma_f32_16x16x32_bf16(a0, b0, acc[0][0], 0, 0, 0);
            acc[0][1] = __builtin_amdgcn_mfma_f32_16x16x32_bf16(a0, b1, acc[0][1], 0, 0, 0);
            acc[1][0] = __builtin_amdgcn_mfma_f32_16x16x32_bf16(a1, b0, acc[1][0], 0, 0, 0);
            acc[1][1] = __builtin_amdgcn_mfma_f32_16x16x32_bf16(a1, b1, acc[1][1], 0, 0, 0);
        }
    }

#pragma unroll
    for (int am = 0; am < 2; am++)
#pragma unroll
        for (int bn = 0; bn < 2; bn++)
#pragma unroll
            for (int r = 0; r < 4; r++) {
                int m = m0 + wm + am * 16 + (lane >> 4) * 4 + r;
                int n = wn + bn * 16 + (lane & 15);
                if (n < N)
                    atomicAdd(&outf[(size_t)m * N + n], acc[am][bn][r]);
            }
}

// ---------------------------------------------------------------------------
// Causal depthwise conv (K=4) + bias + SiLU on [d][ml]. (R12/R14-verbatim)
// ---------------------------------------------------------------------------
__global__ __launch_bounds__(256)
void conv_silu_kernel(const bf16* __restrict__ xp_raw_t,
                      const float* __restrict__ cw, const float* __restrict__ cb,
                      bf16* __restrict__ xp_t)
{
    const int ml = blockIdx.x * 256 + threadIdx.x;
    const int d  = blockIdx.y;
    const int l  = ml & (L_SEQ - 1);
    const size_t row = (size_t)d * ML;
    float s = cb[d];
#pragma unroll
    for (int j = 0; j < 4; j++) {
        if (l - 3 + j >= 0)
            s += __bfloat162float(xp_raw_t[row + ml - 3 + j]) * cw[d * 4 + j];
    }
    float act = s / (1.f + __expf(-s));                 // silu
    xp_t[row + ml] = __float2bfloat16(act);
}

// ---------------------------------------------------------------------------
// dt = softplus(dt_r @ dt_proj_w + b), LDS-tiled (R13/R14-green): 64m x 48d.
// ---------------------------------------------------------------------------
__global__ __launch_bounds__(256)
void dt_kernel(const float* __restrict__ x_dbl, const float* __restrict__ dtw,
               const float* __restrict__ dtb, bf16* __restrict__ dt_t)
{
    __shared__ float xs[64 * 25];
    __shared__ float ws[24 * 48];
    const int tid = threadIdx.x;
    const int m0 = blockIdx.x * 64;
    const int d0 = blockIdx.y * 48;
#pragma unroll
    for (int i = 0; i < 6; i++) {
        int idx = tid + 256 * i;        // < 1536 = 64*24
        int r_ = idx / 24, cc = idx % 24;
        xs[r_ * 25 + cc] = x_dbl[(size_t)(m0 + r_) * 56 + cc];
    }
#pragma unroll
    for (int i = 0; i < 5; i++) {
        int idx = tid + 256 * i;
        if (idx < 24 * 48) {
            int r_ = idx / 48, dd = idx % 48;
            ws[idx] = dtw[r_ * D_INNER + d0 + dd];
        }
    }
    __syncthreads();
#pragma unroll
    for (int i = 0; i < 12; i++) {
        int o = tid + 256 * i;          // < 3072 = 64*48
        int mloc = o & 63, dd = o >> 6; // dd wave-uniform
        float acc = dtb[d0 + dd];
#pragma unroll
        for (int r_ = 0; r_ < 24; r_++)
            acc += xs[mloc * 25 + r_] * ws[r_ * 48 + dd];
        float sp = fmaxf(acc, 0.f) + log1pf(__expf(-fabsf(acc)));
        dt_t[(size_t)(d0 + dd) * ML + m0 + mloc] = __float2bfloat16(sp);
    }
}

// ---------------------------------------------------------------------------
// Chunk-parallel selective scan. R14-green structure; ONLY change: dt/xp
// loads widened to bf16x8 pairs per 16-step sub-group (16 VGPRs live within
// a group only — R8's spill came from 48 regs live across the whole phase).
// Element extracts use compile-time indices under full unroll.
// ---------------------------------------------------------------------------
__global__ __launch_bounds__(1024)
void scan_kernel(const bf16* __restrict__ dt_t, const bf16* __restrict__ xp_t,
                 const float* __restrict__ x_dbl, const bf16* __restrict__ zs_t,
                 const float* __restrict__ A_log, const float* __restrict__ Dp,
                 bf16* __restrict__ y_t)
{
    __shared__ float sP[NCHUNK][D_STATE];
    __shared__ float sH[NCHUNK][D_STATE];
    const int tid = threadIdx.x;
    const int c = tid >> 4;           // chunk 0..63
    const int n = tid & 15;           // state 0..15
    const int g = blockIdx.x;         // (b,d)
    const int b = g / D_INNER;
    const int d = g % D_INNER;
    const float A = -__expf(A_log[d * D_STATE + n]);
    const size_t base_t = (size_t)d * ML + (size_t)b * L_SEQ + (size_t)c * CHLEN;
    const size_t base_m = (size_t)b * L_SEQ + (size_t)c * CHLEN;

    float h = 0.f, P = 1.f;
#pragma unroll
    for (int g2 = 0; g2 < 2; g2++) {
        bf16x8 vdt0 = *(const bf16x8*)&dt_t[base_t + g2 * 16];
        bf16x8 vdt1 = *(const bf16x8*)&dt_t[base_t + g2 * 16 + 8];
        bf16x8 vxp0 = *(const bf16x8*)&xp_t[base_t + g2 * 16];
        bf16x8 vxp1 = *(const bf16x8*)&xp_t[base_t + g2 * 16 + 8];
#pragma unroll
        for (int k = 0; k < 16; k++) {
            const int j = g2 * 16 + k;
            short sdt = (k < 8) ? vdt0[k & 7] : vdt1[k & 7];
            short sxp = (k < 8) ? vxp0[k & 7] : vxp1[k & 7];
            float dtv = __uint_as_float(((unsigned)(unsigned short)sdt) << 16);
            float xpv = __uint_as_float(((unsigned)(unsigned short)sxp) << 16);
            float Bn  = x_dbl[(base_m + j) * 56 + DT_RANK + n];
            float aj = __expf(dtv * A);
            h = aj * h + Bn * (dtv * xpv);
            P *= aj;
        }
    }
    sP[c][n] = P;
    sH[c][n] = h;
    __syncthreads();

    // Kogge-Stone inclusive scan over chunks: compose (P,h) pairs
#pragma unroll
    for (int s = 1; s < NCHUNK; s <<= 1) {
        float p2 = 0.f, h2 = 0.f;
        const bool act = (c >= s);
        if (act) { p2 = sP[c - s][n]; h2 = sH[c - s][n]; }
        __syncthreads();
        if (act) {
            sH[c][n] = sP[c][n] * h2 + sH[c][n];
            sP[c][n] = sP[c][n] * p2;
        }
        __syncthreads();
    }
    const float hinit = (c == 0) ? 0.f : sH[c - 1][n];

    // Phase 3: corrected re-scan (recompute a,u) + butterfly reduce + store
    const float Dd = Dp[d];
    h = hinit;
#pragma unroll
    for (int g2 = 0; g2 < 2; g2++) {
        bf16x8 vdt0 = *(const bf16x8*)&dt_t[base_t + g2 * 16];
        bf16x8 vdt1 = *(const bf16x8*)&dt_t[base_t + g2 * 16 + 8];
        bf16x8 vxp0 = *(const bf16x8*)&xp_t[base_t + g2 * 16];
        bf16x8 vxp1 = *(const bf16x8*)&xp_t[base_t + g2 * 16 + 8];
#pragma unroll
        for (int k = 0; k < 16; k++) {
            const int j = g2 * 16 + k;
            short sdt = (k < 8) ? vdt0[k & 7] : vdt1[k & 7];
            short sxp = (k < 8) ? vxp0[k & 7] : vxp1[k & 7];
            float dtv = __uint_as_float(((unsigned)(unsigned short)sdt) << 16);
            float xpv = __uint_as_float(((unsigned)(unsigned short)sxp) << 16);
            float Bn  = x_dbl[(base_m + j) * 56 + DT_RANK + n];
            float aj = __expf(dtv * A);
            h = aj * h + Bn * (dtv * xpv);
            float Cn = x_dbl[(base_m + j) * 56 + DT_RANK + D_STATE + n];
            float yv = h * Cn;
            yv += __shfl_xor(yv, 1);
            yv += __shfl_xor(yv, 2);
            yv += __shfl_xor(yv, 4);
            yv += __shfl_xor(yv, 8);
            if (n == 0) {
                float y = (yv + xpv * Dd) * __bfloat162float(zs_t[base_t + j]);
                y_t[base_t + j] = __float2bfloat16(y);
            }
        }
    }
}

// ---------------------------------------------------------------------------
extern "C" void kernel_launch(void* const* d_in, const int* in_sizes, int n_in,
                              void* d_out, int out_size, void* d_ws, size_t ws_size,
                              hipStream_t stream)
{
    const float* x         = (const float*)d_in[0];
    const float* in_proj_w = (const float*)d_in[1];
    const float* conv_w    = (const float*)d_in[2];
    const float* conv_b    = (const float*)d_in[3];
    const float* x_proj_w  = (const float*)d_in[4];
    const float* dt_proj_w = (const float*)d_in[5];
    const float* dt_proj_b = (const float*)d_in[6];
    const float* A_log     = (const float*)d_in[7];
    const float* Dvec      = (const float*)d_in[8];
    const float* out_proj_w= (const float*)d_in[9];

    // workspace (all transposed [d][ml] bf16 except x_dbl): ~26.1 MB
    bf16* xp_raw_t = (bf16*)d_ws;                        // [768][ML] (reused as y_t)
    bf16* zs_t     = xp_raw_t + (size_t)ML * D_INNER;    // [768][ML] silu(z)
    bf16* xp_t     = zs_t     + (size_t)ML * D_INNER;    // [768][ML]
    bf16* dt_t     = xp_t     + (size_t)ML * D_INNER;    // [768][ML]
    float* x_dbl   = (float*)(dt_t + (size_t)ML * D_INNER); // [ML][56] fp32
    bf16* y_t      = xp_raw_t;                           // alias (dead after conv)

    dim3 blk(256);

    // 1) in_proj (64x64, proven): -> xp_raw_t | zs_t (transposed)
    gemm_mfma<0, 0><<<dim3(2 * D_INNER / 64, ML / 64), blk, 0, stream>>>(
        x, nullptr, in_proj_w, xp_raw_t, zs_t, nullptr, ML, 2 * D_INNER, D_MODEL);

    // 2) depthwise causal conv + silu
    conv_silu_kernel<<<dim3(ML / 256, D_INNER), blk, 0, stream>>>(
        xp_raw_t, conv_w, conv_b, xp_t);

    // 3) x_proj, K-split x4 with fp32 atomics (x_dbl zeroed first)
    hipMemsetAsync(x_dbl, 0, (size_t)ML * 56 * sizeof(float), stream);
    gemm_xproj_split<<<dim3(4, ML / 64), blk, 0, stream>>>(
        xp_t, x_proj_w, x_dbl, ML, 56, D_INNER);

    // 4) dt_proj + softplus (LDS-tiled) -> dt_t
    dt_kernel<<<dim3(ML / 64, D_INNER / 48), blk, 0, stream>>>(
        x_dbl, dt_proj_w, dt_proj_b, dt_t);

    // 5) chunk-parallel selective scan -> y_t (aliases xp_raw_t)
    scan_kernel<<<B_SZ * D_INNER, 1024, 0, stream>>>(
        dt_t, xp_t, x_dbl, zs_t, A_log, Dvec, y_t);

    // 6) out_proj: A = y_t (transposed), W (768x384) -> d_out fp32
    gemm_mfma<1, 1><<<dim3(D_MODEL / 64, ML / 64), blk, 0, stream>>>(
        nullptr, y_t, out_proj_w, nullptr, nullptr, (float*)d_out, ML, D_MODEL, D_INNER);
}